// Round 6
// baseline (424.327 us; speedup 1.0000x reference)
//
#include <hip/hip_runtime.h>
#include <hip/hip_bf16.h>
#include <stdint.h>

// BOXLoss: N=1e6 rows, G=32 groups. Output = scalar loss.
// Pass B (pack): read is_in_boxes (128MB) once -> 1 bit/entry bitmask (4MB ws),
//                conf[g] = max masked score via REGISTER maxima (no in-loop atomics).
// Pass C (mx):   log-space column max t[g]=conf[g]*log2(s)+log2(iou) in registers,
//                statically-indexed lmax[32]; merge once via monotone uint keys.
// Pass D (loss): focal-loss accumulation; invmx precomputed (mul instead of div).

constexpr float kClamp = 1e-4f;
constexpr uint32_t kNegInfKey = 0x007FFFFFu;  // fkey(-inf)

__device__ inline uint32_t fkey(float f) {    // monotone float -> uint
    uint32_t u = __float_as_uint(f);
    return (u & 0x80000000u) ? ~u : (u | 0x80000000u);
}
__device__ inline float funkey(uint32_t k) {
    uint32_t u = (k & 0x80000000u) ? (k ^ 0x80000000u) : ~k;
    return __uint_as_float(u);
}

__global__ void init_kernel(uint32_t* confbits, uint32_t* mxkeys, float* out) {
    int t = threadIdx.x;
    if (t < 32) { confbits[t] = 0u; mxkeys[t] = kNegInfKey; }
    if (t == 0) out[0] = 0.0f;
}

// Each lane handles one int4 (4 group entries). 8 lanes = 1 row (G=32).
// sub = c&7 == tid&7 (grid stride is a multiple of 8) -> lane owns 4 fixed columns.
template <bool WRITE_BITS>
__global__ void pack_conf_kernel(const int4* __restrict__ boxes4,
                                 const float* __restrict__ scores,
                                 uint32_t* __restrict__ bits,
                                 uint32_t* __restrict__ confbits,
                                 long long nchunks) {
    __shared__ uint32_t conf_lds[32];
    int tid = threadIdx.x;
    if (tid < 32) conf_lds[tid] = 0u;
    __syncthreads();
    int g0 = (tid & 7) * 4;
    float r0 = 0.0f, r1 = 0.0f, r2 = 0.0f, r3 = 0.0f;   // per-lane column maxima
    long long stride = (long long)gridDim.x * blockDim.x;
    for (long long c = (long long)blockIdx.x * blockDim.x + tid; c < nchunks; c += stride) {
        int4 v = boxes4[c];
        uint32_t nib = (uint32_t)(v.x > 0) | ((uint32_t)(v.y > 0) << 1) |
                       ((uint32_t)(v.z > 0) << 2) | ((uint32_t)(v.w > 0) << 3);
        long long row = c >> 3;
        if (WRITE_BITS) {
            uint32_t r = nib << ((tid & 7) * 4);
            r |= __shfl_xor(r, 1);
            r |= __shfl_xor(r, 2);
            r |= __shfl_xor(r, 4);              // 8-lane OR -> full row mask
            if ((tid & 7) == 0) bits[row] = r;
        }
        float s = scores[row];                  // 8-lane broadcast, L1/L2-cached
        r0 = (nib & 1u) ? fmaxf(r0, s) : r0;    // predicated, no atomics
        r1 = (nib & 2u) ? fmaxf(r1, s) : r1;
        r2 = (nib & 4u) ? fmaxf(r2, s) : r2;
        r3 = (nib & 8u) ? fmaxf(r3, s) : r3;
    }
    // one-time merge: 8 lanes per wave share a column set -> shuffle-max first
    for (int off = 8; off < 64; off <<= 1) {
        r0 = fmaxf(r0, __shfl_xor(r0, off));
        r1 = fmaxf(r1, __shfl_xor(r1, off));
        r2 = fmaxf(r2, __shfl_xor(r2, off));
        r3 = fmaxf(r3, __shfl_xor(r3, off));
    }
    if ((tid & 63) < 8) {                       // 8 lanes/wave, 4 atomics each (one-time)
        atomicMax(&conf_lds[g0 + 0], __float_as_uint(r0));  // scores >= 0
        atomicMax(&conf_lds[g0 + 1], __float_as_uint(r1));
        atomicMax(&conf_lds[g0 + 2], __float_as_uint(r2));
        atomicMax(&conf_lds[g0 + 3], __float_as_uint(r3));
    }
    __syncthreads();
    if (tid < 32 && conf_lds[tid]) atomicMax(&confbits[tid], conf_lds[tid]);
}

__device__ inline uint32_t row_mask_from_boxes(const int4* __restrict__ boxes4, int row) {
    uint32_t m = 0;
#pragma unroll
    for (int k = 0; k < 8; ++k) {
        int4 v = boxes4[(long long)row * 8 + k];
        uint32_t nib = (uint32_t)(v.x > 0) | ((uint32_t)(v.y > 0) << 1) |
                       ((uint32_t)(v.z > 0) << 2) | ((uint32_t)(v.w > 0) << 3);
        m |= nib << (k * 4);
    }
    return m;
}

// Column max of log2(raw) = conf[g]*log2(s) + log2(iou); pow(0,0)=1 -> NaN->0 patch.
template <bool USE_BITS>
__global__ void mx_kernel(const uint32_t* __restrict__ bits,
                          const int4* __restrict__ boxes4,
                          const float* __restrict__ scores,
                          const float* __restrict__ iouMap,
                          const uint32_t* __restrict__ confbits,
                          uint32_t* __restrict__ mxkeys, int n) {
    __shared__ float conf_s[32];
    __shared__ uint32_t smax[32];
    int tid = threadIdx.x;
    if (tid < 32) { conf_s[tid] = __uint_as_float(confbits[tid]); smax[tid] = kNegInfKey; }
    __syncthreads();
    float lmax[32];
#pragma unroll
    for (int g = 0; g < 32; ++g) lmax[g] = -__builtin_inff();
    int stride = gridDim.x * blockDim.x;
    for (int row = blockIdx.x * blockDim.x + tid; row < n; row += stride) {
        uint32_t m = USE_BITS ? bits[row] : row_mask_from_boxes(boxes4, row);
        if (!m) continue;
        float l2s = log2f(scores[row]);         // -inf for s==0
        float l2i = log2f(iouMap[row]);         // -inf for iou==0
#pragma unroll
        for (int g = 0; g < 32; ++g) {          // static indexing: stays in VGPRs
            float t0 = conf_s[g] * l2s;
            t0 = (t0 != t0) ? 0.0f : t0;        // 0*-inf (pow(0,0)=1) -> log contrib 0
            float t = t0 + l2i;
            lmax[g] = (m & (1u << g)) ? fmaxf(lmax[g], t) : lmax[g];
        }
    }
#pragma unroll
    for (int g = 0; g < 32; ++g)                // one-time merge (32 atomics/lane)
        atomicMax(&smax[g], fkey(lmax[g]));
    __syncthreads();
    if (tid < 32) atomicMax(&mxkeys[tid], smax[tid]);
}

template <bool USE_BITS>
__global__ void loss_kernel(const uint32_t* __restrict__ bits,
                            const int4* __restrict__ boxes4,
                            const float* __restrict__ logits,
                            const float* __restrict__ scores,
                            const float* __restrict__ iouMap,
                            const uint32_t* __restrict__ confbits,
                            const uint32_t* __restrict__ mxkeys,
                            const void* __restrict__ denom_ptr,
                            float* __restrict__ out, int n) {
    __shared__ float conf_s[32];
    __shared__ float invmx[32];
    __shared__ float wsum[4];
    int tid = threadIdx.x;
    if (tid < 32) {
        conf_s[tid] = __uint_as_float(confbits[tid]);
        float mx = exp2f(funkey(mxkeys[tid]));  // -inf key -> mx=0 (unused columns)
        invmx[tid] = 1.0f / (mx + kClamp);
    }
    __syncthreads();
    float acc = 0.0f;
    int stride = gridDim.x * blockDim.x;
    for (int row = blockIdx.x * blockDim.x + tid; row < n; row += stride) {
        uint32_t m = USE_BITS ? bits[row] : row_mask_from_boxes(boxes4, row);
        float x = logits[row];
        float p = 1.0f / (1.0f + expf(-x));
        p = fminf(fmaxf(p, kClamp), 1.0f - kClamp);
        if (!m) {
            acc -= logf(1.0f - p) * p * p * 0.75f;   // (1-FOCAL_ALPHA)
            continue;
        }
        float l2s = log2f(scores[row]);
        float l2i = log2f(iouMap[row]);
        float logp = logf(p);
        float log1mp = logf(1.0f - p);
        float omp = 1.0f - p;
        while (m) {
            int g = __ffs(m) - 1;
            m &= m - 1;
            float t0 = conf_s[g] * l2s;
            t0 = (t0 != t0) ? 0.0f : t0;
            float raw = exp2f(t0 + l2i);        // = s^conf * iou
            float wc = (raw + kClamp) * invmx[g];
            wc = fminf(fmaxf(wc, kClamp), 1.0f - kClamp);
            float a1 = wc * omp;                // pos: -logp * (wc*(1-p))^2
            float a2 = (1.0f - wc) * p;         // boxneg: -log1mp * ((1-wc)*p)^2
            acc -= (logp * a1 * a1 + log1mp * a2 * a2) * 0.25f;  // FOCAL_ALPHA
        }
    }
    for (int off = 32; off > 0; off >>= 1) acc += __shfl_down(acc, off);
    if ((tid & 63) == 0) wsum[tid >> 6] = acc;
    __syncthreads();
    if (tid == 0) {
        int iv = *(const int*)denom_ptr;        // num_pos_avg: int or float bits
        float fv = *(const float*)denom_ptr;
        float denom = (iv > 0 && iv < (1 << 24)) ? (float)iv : fv;
        float tot = (wsum[0] + wsum[1] + wsum[2] + wsum[3]) / denom;
        atomicAdd(out, tot);
    }
}

extern "C" void kernel_launch(void* const* d_in, const int* in_sizes, int n_in,
                              void* d_out, int out_size, void* d_ws, size_t ws_size,
                              hipStream_t stream) {
    const float* logits = (const float*)d_in[0];
    const float* scores = (const float*)d_in[1];
    const float* iou    = (const float*)d_in[2];
    const int4*  boxes4 = (const int4*)d_in[3];
    const void*  npa    = d_in[4];
    float* out = (float*)d_out;

    int n = in_sizes[0];                       // 1e6 rows
    long long gtotal = in_sizes[3];            // n * 32
    long long nchunks = gtotal / 4;            // int4 chunks

    uint32_t* confbits = (uint32_t*)d_ws;      // [0..31]
    uint32_t* mxkeys   = confbits + 32;        // [32..63]
    uint32_t* bits     = confbits + 64;        // +256B, n uint32
    bool use_bits = ws_size >= (size_t)n * 4 + 256;

    init_kernel<<<1, 64, 0, stream>>>(confbits, mxkeys, out);

    if (use_bits) {
        pack_conf_kernel<true><<<2048, 256, 0, stream>>>(boxes4, scores, bits, confbits, nchunks);
        mx_kernel<true><<<2048, 256, 0, stream>>>(bits, nullptr, scores, iou, confbits, mxkeys, n);
        loss_kernel<true><<<2048, 256, 0, stream>>>(bits, nullptr, logits, scores, iou,
                                                    confbits, mxkeys, npa, out, n);
    } else {
        pack_conf_kernel<false><<<2048, 256, 0, stream>>>(boxes4, scores, nullptr, confbits, nchunks);
        mx_kernel<false><<<2048, 256, 0, stream>>>(nullptr, boxes4, scores, iou, confbits, mxkeys, n);
        loss_kernel<false><<<2048, 256, 0, stream>>>(nullptr, boxes4, logits, scores, iou,
                                                     confbits, mxkeys, npa, out, n);
    }
}

// Round 7
// 279.222 us; speedup vs baseline: 1.5197x; 1.5197x over previous
//
#include <hip/hip_runtime.h>
#include <hip/hip_bf16.h>
#include <stdint.h>

// BOXLoss: N=1e6 rows, G=32 groups. Output = scalar loss.
// Pass B (pack): read is_in_boxes (128MB) once -> 1 bit/entry bitmask (4MB ws),
//                conf[g] = max masked score via register maxima.
// Pass C (mx):   log-space column max t[g]=conf[g]*log2(s)+log2(iou).
//                4 threads/row x 8 columns each -> lmax[8] registers (NO spill;
//                r6's lmax[32] spilled to scratch at VGPR_Count=40 -> 180us).
//                Merge: butterfly shuffle -> LDS (no atomics) -> 32 global atomics/block.
// Pass D (loss): focal-loss accumulation; invmx precomputed.

constexpr float kClamp = 1e-4f;
constexpr uint32_t kNegInfKey = 0x007FFFFFu;  // fkey(-inf)

__device__ inline uint32_t fkey(float f) {    // monotone float -> uint
    uint32_t u = __float_as_uint(f);
    return (u & 0x80000000u) ? ~u : (u | 0x80000000u);
}
__device__ inline float funkey(uint32_t k) {
    uint32_t u = (k & 0x80000000u) ? (k ^ 0x80000000u) : ~k;
    return __uint_as_float(u);
}

__global__ void init_kernel(uint32_t* confbits, uint32_t* mxkeys, float* out) {
    int t = threadIdx.x;
    if (t < 32) { confbits[t] = 0u; mxkeys[t] = kNegInfKey; }
    if (t == 0) out[0] = 0.0f;
}

// Each lane handles one int4 (4 group entries). 8 lanes = 1 row (G=32).
template <bool WRITE_BITS>
__global__ void pack_conf_kernel(const int4* __restrict__ boxes4,
                                 const float* __restrict__ scores,
                                 uint32_t* __restrict__ bits,
                                 uint32_t* __restrict__ confbits,
                                 long long nchunks) {
    __shared__ uint32_t conf_lds[32];
    int tid = threadIdx.x;
    if (tid < 32) conf_lds[tid] = 0u;
    __syncthreads();
    int g0 = (tid & 7) * 4;
    float r0 = 0.0f, r1 = 0.0f, r2 = 0.0f, r3 = 0.0f;   // per-lane column maxima
    long long stride = (long long)gridDim.x * blockDim.x;
    for (long long c = (long long)blockIdx.x * blockDim.x + tid; c < nchunks; c += stride) {
        int4 v = boxes4[c];
        uint32_t nib = (uint32_t)(v.x > 0) | ((uint32_t)(v.y > 0) << 1) |
                       ((uint32_t)(v.z > 0) << 2) | ((uint32_t)(v.w > 0) << 3);
        long long row = c >> 3;
        if (WRITE_BITS) {
            uint32_t r = nib << ((tid & 7) * 4);
            r |= __shfl_xor(r, 1);
            r |= __shfl_xor(r, 2);
            r |= __shfl_xor(r, 4);              // 8-lane OR -> full row mask
            if ((tid & 7) == 0) bits[row] = r;
        }
        float s = scores[row];                  // 8-lane broadcast, cached
        r0 = (nib & 1u) ? fmaxf(r0, s) : r0;
        r1 = (nib & 2u) ? fmaxf(r1, s) : r1;
        r2 = (nib & 4u) ? fmaxf(r2, s) : r2;
        r3 = (nib & 8u) ? fmaxf(r3, s) : r3;
    }
    for (int off = 8; off < 64; off <<= 1) {    // lanes sharing a column set
        r0 = fmaxf(r0, __shfl_xor(r0, off));
        r1 = fmaxf(r1, __shfl_xor(r1, off));
        r2 = fmaxf(r2, __shfl_xor(r2, off));
        r3 = fmaxf(r3, __shfl_xor(r3, off));
    }
    if ((tid & 63) < 8) {                       // one-time, 8 lanes/wave
        atomicMax(&conf_lds[g0 + 0], __float_as_uint(r0));  // scores >= 0
        atomicMax(&conf_lds[g0 + 1], __float_as_uint(r1));
        atomicMax(&conf_lds[g0 + 2], __float_as_uint(r2));
        atomicMax(&conf_lds[g0 + 3], __float_as_uint(r3));
    }
    __syncthreads();
    if (tid < 32 && conf_lds[tid]) atomicMax(&confbits[tid], conf_lds[tid]);
}

__device__ inline uint32_t row_mask_from_boxes(const int4* __restrict__ boxes4, int row) {
    uint32_t m = 0;
#pragma unroll
    for (int k = 0; k < 8; ++k) {
        int4 v = boxes4[(long long)row * 8 + k];
        uint32_t nib = (uint32_t)(v.x > 0) | ((uint32_t)(v.y > 0) << 1) |
                       ((uint32_t)(v.z > 0) << 2) | ((uint32_t)(v.w > 0) << 3);
        m |= nib << (k * 4);
    }
    return m;
}

// 4 threads per row; thread (tid&3) owns columns [chunk*8, chunk*8+8).
template <bool USE_BITS>
__global__ void mx_kernel(const uint32_t* __restrict__ bits,
                          const int4* __restrict__ boxes4,
                          const float* __restrict__ scores,
                          const float* __restrict__ iouMap,
                          const uint32_t* __restrict__ confbits,
                          uint32_t* __restrict__ mxkeys, int n) {
    __shared__ float conf_s[32];
    __shared__ float smax_w[4][32];             // [wave][column], no atomics
    int tid = threadIdx.x;
    if (tid < 32) conf_s[tid] = __uint_as_float(confbits[tid]);
    __syncthreads();
    int chunk = tid & 3;
    float cf[8];
#pragma unroll
    for (int k = 0; k < 8; ++k) cf[k] = conf_s[chunk * 8 + k];
    float lmax[8];
#pragma unroll
    for (int k = 0; k < 8; ++k) lmax[k] = -__builtin_inff();

    int slots = (gridDim.x * blockDim.x) >> 2;  // threads/4 row-slots
    for (int row = (blockIdx.x * blockDim.x + tid) >> 2; row < n; row += slots) {
        uint32_t m = USE_BITS ? bits[row] : row_mask_from_boxes(boxes4, row);
        uint32_t mc = (m >> (chunk * 8)) & 0xFFu;
        if (!mc) continue;
        float l2s = log2f(scores[row]);         // -inf for s==0
        float l2i = log2f(iouMap[row]);
#pragma unroll
        for (int k = 0; k < 8; ++k) {
            float t0 = cf[k] * l2s;
            t0 = (t0 != t0) ? 0.0f : t0;        // 0*-inf (pow(0,0)=1) -> 0
            float t = t0 + l2i;
            lmax[k] = (mc & (1u << k)) ? fmaxf(lmax[k], t) : lmax[k];
        }
    }
    // butterfly over lanes sharing a chunk (lane ^ {4,8,16,32})
#pragma unroll
    for (int off = 4; off < 64; off <<= 1) {
#pragma unroll
        for (int k = 0; k < 8; ++k) lmax[k] = fmaxf(lmax[k], __shfl_xor(lmax[k], off));
    }
    int wave = tid >> 6, lane = tid & 63;
    if (lane < 4) {                             // lane == its chunk id
#pragma unroll
        for (int k = 0; k < 8; ++k) smax_w[wave][lane * 8 + k] = lmax[k];
    }
    __syncthreads();
    if (tid < 32) {
        float v = fmaxf(fmaxf(smax_w[0][tid], smax_w[1][tid]),
                        fmaxf(smax_w[2][tid], smax_w[3][tid]));
        uint32_t k = fkey(v);
        if (k != kNegInfKey) atomicMax(&mxkeys[tid], k);
    }
}

template <bool USE_BITS>
__global__ void loss_kernel(const uint32_t* __restrict__ bits,
                            const int4* __restrict__ boxes4,
                            const float* __restrict__ logits,
                            const float* __restrict__ scores,
                            const float* __restrict__ iouMap,
                            const uint32_t* __restrict__ confbits,
                            const uint32_t* __restrict__ mxkeys,
                            const void* __restrict__ denom_ptr,
                            float* __restrict__ out, int n) {
    __shared__ float conf_s[32];
    __shared__ float invmx[32];
    __shared__ float wsum[4];
    int tid = threadIdx.x;
    if (tid < 32) {
        conf_s[tid] = __uint_as_float(confbits[tid]);
        float mx = exp2f(funkey(mxkeys[tid]));  // -inf key -> mx=0 (unused cols)
        invmx[tid] = 1.0f / (mx + kClamp);
    }
    __syncthreads();
    float acc = 0.0f;
    int stride = gridDim.x * blockDim.x;
    for (int row = blockIdx.x * blockDim.x + tid; row < n; row += stride) {
        uint32_t m = USE_BITS ? bits[row] : row_mask_from_boxes(boxes4, row);
        float x = logits[row];
        float p = 1.0f / (1.0f + expf(-x));
        p = fminf(fmaxf(p, kClamp), 1.0f - kClamp);
        if (!m) {
            acc -= logf(1.0f - p) * p * p * 0.75f;   // (1-FOCAL_ALPHA)
            continue;
        }
        float l2s = log2f(scores[row]);
        float l2i = log2f(iouMap[row]);
        float logp = logf(p);
        float log1mp = logf(1.0f - p);
        float omp = 1.0f - p;
        while (m) {
            int g = __ffs(m) - 1;
            m &= m - 1;
            float t0 = conf_s[g] * l2s;
            t0 = (t0 != t0) ? 0.0f : t0;
            float raw = exp2f(t0 + l2i);        // = s^conf * iou
            float wc = (raw + kClamp) * invmx[g];
            wc = fminf(fmaxf(wc, kClamp), 1.0f - kClamp);
            float a1 = wc * omp;                // pos: -logp * (wc*(1-p))^2
            float a2 = (1.0f - wc) * p;         // boxneg: -log1mp * ((1-wc)*p)^2
            acc -= (logp * a1 * a1 + log1mp * a2 * a2) * 0.25f;  // FOCAL_ALPHA
        }
    }
    for (int off = 32; off > 0; off >>= 1) acc += __shfl_down(acc, off);
    if ((tid & 63) == 0) wsum[tid >> 6] = acc;
    __syncthreads();
    if (tid == 0) {
        int iv = *(const int*)denom_ptr;        // num_pos_avg: int or float bits
        float fv = *(const float*)denom_ptr;
        float denom = (iv > 0 && iv < (1 << 24)) ? (float)iv : fv;
        float tot = (wsum[0] + wsum[1] + wsum[2] + wsum[3]) / denom;
        atomicAdd(out, tot);
    }
}

extern "C" void kernel_launch(void* const* d_in, const int* in_sizes, int n_in,
                              void* d_out, int out_size, void* d_ws, size_t ws_size,
                              hipStream_t stream) {
    const float* logits = (const float*)d_in[0];
    const float* scores = (const float*)d_in[1];
    const float* iou    = (const float*)d_in[2];
    const int4*  boxes4 = (const int4*)d_in[3];
    const void*  npa    = d_in[4];
    float* out = (float*)d_out;

    int n = in_sizes[0];                       // 1e6 rows
    long long gtotal = in_sizes[3];            // n * 32
    long long nchunks = gtotal / 4;            // int4 chunks

    uint32_t* confbits = (uint32_t*)d_ws;      // [0..31]
    uint32_t* mxkeys   = confbits + 32;        // [32..63]
    uint32_t* bits     = confbits + 64;        // +256B, n uint32
    bool use_bits = ws_size >= (size_t)n * 4 + 256;

    init_kernel<<<1, 64, 0, stream>>>(confbits, mxkeys, out);

    if (use_bits) {
        pack_conf_kernel<true><<<2048, 256, 0, stream>>>(boxes4, scores, bits, confbits, nchunks);
        mx_kernel<true><<<512, 256, 0, stream>>>(bits, nullptr, scores, iou, confbits, mxkeys, n);
        loss_kernel<true><<<1024, 256, 0, stream>>>(bits, nullptr, logits, scores, iou,
                                                    confbits, mxkeys, npa, out, n);
    } else {
        pack_conf_kernel<false><<<2048, 256, 0, stream>>>(boxes4, scores, nullptr, confbits, nchunks);
        mx_kernel<false><<<512, 256, 0, stream>>>(nullptr, boxes4, scores, iou, confbits, mxkeys, n);
        loss_kernel<false><<<1024, 256, 0, stream>>>(nullptr, boxes4, logits, scores, iou,
                                                     confbits, mxkeys, npa, out, n);
    }
}